// Round 1
// baseline (265.133 us; speedup 1.0000x reference)
//
#include <hip/hip_runtime.h>
#include <math.h>

// HiPPO-LegS kernel: K[d, l] = C[d]^T A_bar^l B_bar[d], D=1024, N=64, L=4096.
// Sqrt-decomposition l = 64q + r:
//   W[d,r,:] = C[d]^T A_bar^r          (via G_r = A_bar^r)
//   X[d,q,:] = (A_bar^64)^q B_bar[d]   (via H_q = S^q, S = A_bar^64)
//   K[d, 64q+r] = sum_n W[d,r,n] X[d,q,n]
// G_r / H_q built by binary exponentiation from squarings S_j = A_bar^(2^j).

#define NS 64
#define DM 1024
#define LL 4096

// ws layout (float offsets). Total 9,031,744 floats = 36.1 MB.
#define WS_DT     0
#define WS_S      64                       // 12 matrices of 4096
#define WS_MINVT  (WS_S + 12*4096)         // 49216
#define WS_BBAR   (WS_MINVT + 4096)        // 53312, 1024x64
#define WS_G      (WS_BBAR + DM*NS)        // 118848, 64 x 4096 (G_r row-major)
#define WS_HT     (WS_G + 64*4096)         // 380992, 64 x 4096 (H_q transposed)
#define WS_W      (WS_HT + 64*4096)        // 643136, [d][r][n]
#define WS_X      (WS_W + DM*LL)           // 4837440, [d][q][n]

// ---------------------------------------------------------------------------
// K1: one block. dt, Gauss-Jordan inverse of M = I - (dt/2)A (lower-tri, no
// pivoting needed: diag >= 1.05), A_bar = Minv @ P, 12 squarings S_j.
// LDS: aug 64x128 (32KB) + bufA/bufB 64x64 (16KB each) = 64KB exactly.
// ---------------------------------------------------------------------------
__global__ __launch_bounds__(1024) void k_setup(const float* __restrict__ A,
                                                const float* __restrict__ logdt,
                                                float* __restrict__ ws) {
  __shared__ __align__(16) float aug[64 * 128];
  __shared__ __align__(16) float bufA[64 * 64];
  __shared__ __align__(16) float bufB[64 * 64];
  const int tid = threadIdx.x;
  const float dt = expf(logdt[0]);
  const float hdt = 0.5f * dt;
  if (tid == 0) ws[WS_DT] = dt;

  // build [M | I]
  for (int idx = tid; idx < 64 * 128; idx += 1024) {
    int i = idx >> 7, j = idx & 127;
    float v;
    if (j < 64) v = ((i == j) ? 1.f : 0.f) - hdt * A[i * 64 + j];
    else        v = (i == (j - 64)) ? 1.f : 0.f;
    aug[idx] = v;
  }
  __syncthreads();

  // Gauss-Jordan, no row normalization (left half ends diagonal).
  const int jcol = tid & 127, ibase = tid >> 7;
  for (int k = 0; k < 64; ++k) {
    float invp = 1.0f / aug[k * 128 + k];
    float f[8];
#pragma unroll
    for (int e = 0; e < 8; ++e) f[e] = aug[(8 * e + ibase) * 128 + k] * invp;
    __syncthreads();
#pragma unroll
    for (int e = 0; e < 8; ++e) {
      int i = 8 * e + ibase;
      if (i != k) aug[i * 128 + jcol] -= f[e] * aug[k * 128 + jcol];
    }
    __syncthreads();
  }

  // Minv[i][j] = right[i][j] / diag[i]; stash into left half.
  {
    float vals[4];
    int ii[4], jj[4];
#pragma unroll
    for (int e = 0; e < 4; ++e) {
      int idx = tid + 1024 * e;
      int i = idx >> 6, j = idx & 63;
      ii[e] = i; jj[e] = j;
      vals[e] = aug[i * 128 + 64 + j] / aug[i * 128 + i];
    }
    __syncthreads();
#pragma unroll
    for (int e = 0; e < 4; ++e) aug[ii[e] * 128 + jj[e]] = vals[e];
    // P = I + hdt*A into bufB
    for (int idx = tid; idx < 4096; idx += 1024) {
      int i = idx >> 6, j = idx & 63;
      bufB[idx] = ((i == j) ? 1.f : 0.f) + hdt * A[idx];
    }
    __syncthreads();
  }

  // MinvT out (one-time transposed LDS read; conflicts negligible)
  for (int idx = tid; idx < 4096; idx += 1024) {
    int k = idx >> 6, n = idx & 63;
    ws[WS_MINVT + idx] = aug[n * 128 + k];
  }

  // A_bar = Minv @ P -> bufA
  {
    float acc[4] = {0.f, 0.f, 0.f, 0.f};
    int j = tid & 63;
    for (int k = 0; k < 64; ++k) {
      float v = bufB[k * 64 + j];
#pragma unroll
      for (int m = 0; m < 4; ++m)
        acc[m] += aug[((tid >> 6) + 16 * m) * 128 + k] * v;
    }
    __syncthreads();
#pragma unroll
    for (int m = 0; m < 4; ++m) bufA[((tid >> 6) + 16 * m) * 64 + j] = acc[m];
  }
  __syncthreads();

  // 12 squarings: S_j = A_bar^(2^j), ping-pong bufA<->bufB.
  float* cur = bufA;
  float* nxt = bufB;
  for (int sj = 0; sj < 12; ++sj) {
    for (int idx = tid; idx < 4096; idx += 1024) ws[WS_S + sj * 4096 + idx] = cur[idx];
    if (sj == 11) break;
    float acc[4] = {0.f, 0.f, 0.f, 0.f};
    int j = tid & 63;
    for (int k = 0; k < 64; ++k) {
      float v = cur[k * 64 + j];
#pragma unroll
      for (int m = 0; m < 4; ++m)
        acc[m] += cur[((tid >> 6) + 16 * m) * 64 + k] * v;
    }
#pragma unroll
    for (int m = 0; m < 4; ++m) nxt[((tid >> 6) + 16 * m) * 64 + j] = acc[m];
    __syncthreads();
    float* t = cur; cur = nxt; nxt = t;
  }
}

// ---------------------------------------------------------------------------
// K2: 144 blocks x 256.
//   p in [0,64):    G_r  = prod S_j over set bits of r   (row-major)
//   p in [64,128):  H_q^T, H_q = prod S_{6+j} over bits  (transposed store)
//   p in [128,144): B_bar chunk of 64 rows: dt * B @ Minv^T
// ---------------------------------------------------------------------------
__global__ __launch_bounds__(256) void k_powers(const float* __restrict__ Bg,
                                                float* __restrict__ ws) {
  __shared__ __align__(16) float sm[NS * NS];
  __shared__ __align__(16) float ra[NS * NS];
  __shared__ __align__(16) float rb[NS * NS];
  const int p = blockIdx.x, tid = threadIdx.x;
  const float* S = ws + WS_S;

  if (p < 128) {
    const int chain = p >> 6, r = p & 63;
    for (int idx = tid; idx < NS * NS; idx += 256)
      ra[idx] = ((idx >> 6) == (idx & 63)) ? 1.f : 0.f;
    float* cur = ra;
    float* nxt = rb;
    for (int j = 0; j < 6; ++j) {
      if ((r >> j) & 1) {  // block-uniform branch
        __syncthreads();
        for (int idx = tid; idx < NS * NS; idx += 256)
          sm[idx] = S[(chain * 6 + j) * 4096 + idx];
        __syncthreads();
        const int jj = tid & 63;
        float acc[16];
#pragma unroll
        for (int m = 0; m < 16; ++m) acc[m] = 0.f;
        for (int k = 0; k < NS; ++k) {
          float v = sm[k * 64 + jj];
#pragma unroll
          for (int m = 0; m < 16; ++m)
            acc[m] += cur[((tid >> 6) + 4 * m) * 64 + k] * v;
        }
#pragma unroll
        for (int m = 0; m < 16; ++m) nxt[((tid >> 6) + 4 * m) * 64 + jj] = acc[m];
        float* t = cur; cur = nxt; nxt = t;
      }
    }
    __syncthreads();
    if (chain == 0) {
      float* G = ws + WS_G + r * 4096;
      for (int idx = tid; idx < NS * NS; idx += 256) G[idx] = cur[idx];
    } else {
      float* HT = ws + WS_HT + r * 4096;
      for (int idx = tid; idx < NS * NS; idx += 256)
        HT[idx] = cur[(idx & 63) * 64 + (idx >> 6)];  // transpose
    }
  } else {
    // B_bar chunk
    const int d0 = (p - 128) * 64;
    const float dtv = ws[WS_DT];
    for (int idx = tid; idx < NS * NS; idx += 256) sm[idx] = ws[WS_MINVT + idx];
    for (int idx = tid; idx < NS * NS; idx += 256) ra[idx] = Bg[d0 * 64 + idx];
    __syncthreads();
    const int n = tid & 63;
    float acc[16];
#pragma unroll
    for (int m = 0; m < 16; ++m) acc[m] = 0.f;
    for (int k = 0; k < NS; ++k) {
      float v = sm[k * 64 + n];
#pragma unroll
      for (int m = 0; m < 16; ++m)
        acc[m] += ra[((tid >> 6) + 4 * m) * 64 + k] * v;
    }
#pragma unroll
    for (int m = 0; m < 16; ++m) {
      int i = (tid >> 6) + 4 * m;
      ws[WS_BBAR + (d0 + i) * 64 + n] = dtv * acc[m];
    }
  }
}

// ---------------------------------------------------------------------------
// K3: 2048 blocks x 256. chain0: W[d0.., r, :] = C_chunk @ G_r
//                        chain1: X[d0.., q, :] = Bbar_chunk @ H_q^T
// ---------------------------------------------------------------------------
__global__ __launch_bounds__(256) void k_expand(const float* __restrict__ Cg,
                                                float* __restrict__ ws) {
  __shared__ __align__(16) float mat[NS * NS];
  __shared__ __align__(16) float src[NS * NS];
  const int p = blockIdx.x, tid = threadIdx.x;
  const int chain = p >> 10, rr = (p >> 4) & 63, d0 = (p & 15) * 64;
  const float* msrc = ws + (chain ? WS_HT : WS_G) + rr * 4096;
  const float* vsrc = chain ? (ws + WS_BBAR + d0 * 64) : (Cg + d0 * 64);
  for (int idx = tid; idx < NS * NS; idx += 256) {
    mat[idx] = msrc[idx];
    src[idx] = vsrc[idx];
  }
  __syncthreads();
  const int n = tid & 63;
  float acc[16];
#pragma unroll
  for (int m = 0; m < 16; ++m) acc[m] = 0.f;
  for (int k = 0; k < NS; k += 4) {
    float v0 = mat[(k + 0) * 64 + n];
    float v1 = mat[(k + 1) * 64 + n];
    float v2 = mat[(k + 2) * 64 + n];
    float v3 = mat[(k + 3) * 64 + n];
#pragma unroll
    for (int m = 0; m < 16; ++m) {
      int i = (tid >> 6) + 4 * m;
      const float4 s4 = *(const float4*)&src[i * 64 + k];  // wave-uniform b128
      acc[m] += s4.x * v0 + s4.y * v1 + s4.z * v2 + s4.w * v3;
    }
  }
  float* dst = ws + (chain ? WS_X : WS_W);
#pragma unroll
  for (int m = 0; m < 16; ++m) {
    int i = (tid >> 6) + 4 * m;
    dst[(d0 + i) * 4096 + rr * 64 + n] = acc[m];
  }
}

// ---------------------------------------------------------------------------
// K4: 1024 blocks x 256, one block per d.
// K[d, 64q+r] = sum_n W[d,r,n] X[d,q,n]; + D[d] at l==0.
// W staged with stride 68 so lane-varying-r float4 reads are bank-benign.
// ---------------------------------------------------------------------------
__global__ __launch_bounds__(256) void k_contract(const float* __restrict__ Dg,
                                                  const float* __restrict__ ws,
                                                  float* __restrict__ out) {
  __shared__ __align__(16) float Wl[64 * 68];
  __shared__ __align__(16) float Xl[64 * 64];
  const int d = blockIdx.x, tid = threadIdx.x;
  const float* Wg = ws + WS_W + d * 4096;
  const float* Xg = ws + WS_X + d * 4096;
  for (int idx = tid; idx < 4096; idx += 256) {
    Wl[(idx >> 6) * 68 + (idx & 63)] = Wg[idx];
    Xl[idx] = Xg[idx];
  }
  __syncthreads();
  const int r = tid & 63, w = tid >> 6;
  float acc[16];
#pragma unroll
  for (int m = 0; m < 16; ++m) acc[m] = 0.f;
  for (int nn = 0; nn < 64; nn += 4) {
    const float4 wv = *(const float4*)&Wl[r * 68 + nn];
#pragma unroll
    for (int m = 0; m < 16; ++m) {
      int q = w + 4 * m;
      const float4 xv = *(const float4*)&Xl[q * 64 + nn];  // wave-uniform
      acc[m] += wv.x * xv.x + wv.y * xv.y + wv.z * xv.z + wv.w * xv.w;
    }
  }
  const float dval = Dg[d];
#pragma unroll
  for (int m = 0; m < 16; ++m) {
    int q = w + 4 * m, l = q * 64 + r;
    out[d * 4096 + l] = acc[m] + ((l == 0) ? dval : 0.f);
  }
}

extern "C" void kernel_launch(void* const* d_in, const int* in_sizes, int n_in,
                              void* d_out, int out_size, void* d_ws, size_t ws_size,
                              hipStream_t stream) {
  const float* A     = (const float*)d_in[0];  // A_ct 64x64
  const float* B     = (const float*)d_in[1];  // 1024x64
  const float* C     = (const float*)d_in[2];  // 1024x64
  const float* Dv    = (const float*)d_in[3];  // 1024
  const float* logdt = (const float*)d_in[4];  // scalar
  float* ws  = (float*)d_ws;                   // needs 36.2 MB
  float* out = (float*)d_out;                  // 1024*4096 fp32

  hipLaunchKernelGGL(k_setup,    dim3(1),    dim3(1024), 0, stream, A, logdt, ws);
  hipLaunchKernelGGL(k_powers,   dim3(144),  dim3(256),  0, stream, B, ws);
  hipLaunchKernelGGL(k_expand,   dim3(2048), dim3(256),  0, stream, C, ws);
  hipLaunchKernelGGL(k_contract, dim3(1024), dim3(256),  0, stream, Dv, ws, out);
}

// Round 2
// 227.299 us; speedup vs baseline: 1.1665x; 1.1665x over previous
//
#include <hip/hip_runtime.h>
#include <math.h>

// HiPPO-LegS kernel: K[d, l] = C[d]^T A_bar^l B_bar[d], D=1024, N=64, L=4096.
// l = 64q + r decomposition; G_r = A_bar^r, H_q = (A_bar^64)^q via squarings
// S_j = A_bar^(2^j), j=0..11.
// Round 2: all matmuls register-tiled (8x4 / 8x(4+4) / 4x16) with pad-68 LDS
// and interleaved row mappings for conflict-free b128 reads; Gauss-Jordan
// replaced by recursive-doubling lower-triangular inverse; A_bar = 2*Minv - I.

#define PAD 68

// ws layout (float offsets). Total 9,031,744 floats = 36.1 MB.
#define WS_DT     0
#define WS_S      64                       // 12 matrices of 4096
#define WS_MINVT  (WS_S + 12*4096)         // 49216
#define WS_BBAR   (WS_MINVT + 4096)        // 53312, 1024x64
#define WS_G      (WS_BBAR + 1024*64)      // 118848, 64 x 4096 (G_r row-major [k][n])
#define WS_HT     (WS_G + 64*4096)         // 380992, 64 x 4096 (H_q transposed: [k][n] = H[n][k])
#define WS_W      (WS_HT + 64*4096)        // 643136, [d][r][n]
#define WS_X      (WS_W + 1024*4096)       // 4837440, [d][q][n]

__device__ __forceinline__ float f4c(const float4 v, int kk) {
  return kk == 0 ? v.x : kk == 1 ? v.y : kk == 2 ? v.z : v.w;
}

// 64x64x64 matmul c = a @ b, both operands LDS pad-68, output LDS pad-68.
// 128 threads, 8x4 register tiles, rows interleaved (ty + 8*ii) so the 8
// a-side b128 reads start at banks 4*ty+k (distinct); b-side spans 16 cols
// groups -> 2-way (free).
__device__ __forceinline__ void mm64_128(const float* __restrict__ a,
                                         const float* __restrict__ b,
                                         float* __restrict__ c, int tid) {
  const int tx = tid & 15;   // col group, n0 = 4*tx
  const int ty = tid >> 4;   // 0..7 row base
  const int n0 = tx * 4;
  float4 acc[8];
#pragma unroll
  for (int ii = 0; ii < 8; ++ii) acc[ii] = make_float4(0.f, 0.f, 0.f, 0.f);
  for (int k = 0; k < 64; k += 4) {
    float4 av[8], bv[4];
#pragma unroll
    for (int ii = 0; ii < 8; ++ii)
      av[ii] = *(const float4*)&a[(ty + 8 * ii) * PAD + k];
#pragma unroll
    for (int kk = 0; kk < 4; ++kk)
      bv[kk] = *(const float4*)&b[(k + kk) * PAD + n0];
#pragma unroll
    for (int kk = 0; kk < 4; ++kk) {
#pragma unroll
      for (int ii = 0; ii < 8; ++ii) {
        const float s = f4c(av[ii], kk);
        acc[ii].x += s * bv[kk].x;
        acc[ii].y += s * bv[kk].y;
        acc[ii].z += s * bv[kk].z;
        acc[ii].w += s * bv[kk].w;
      }
    }
  }
#pragma unroll
  for (int ii = 0; ii < 8; ++ii)
    *(float4*)&c[(ty + 8 * ii) * PAD + n0] = acc[ii];
}

// global row-major 64x64 -> LDS pad-68
template <int NT>
__device__ __forceinline__ void stage(const float* __restrict__ g,
                                      float* __restrict__ l, int tid) {
  for (int e = tid; e < 1024; e += NT) {
    const int row = e >> 4, c4 = (e & 15) << 2;
    *(float4*)&l[row * PAD + c4] = *(const float4*)&g[row * 64 + c4];
  }
}

// LDS pad-68 -> global row-major 64x64 (optional scale)
template <int NT>
__device__ __forceinline__ void unstage(const float* __restrict__ l,
                                        float* __restrict__ g, int tid,
                                        float scale) {
  for (int e = tid; e < 1024; e += NT) {
    const int row = e >> 4, c4 = (e & 15) << 2;
    float4 v = *(const float4*)&l[row * PAD + c4];
    v.x *= scale; v.y *= scale; v.z *= scale; v.w *= scale;
    *(float4*)&g[row * 64 + c4] = v;
  }
}

// ---------------------------------------------------------------------------
// K1: one block, 128 threads.
// dt; recursive-doubling inverse of lower-triangular M = I - (dt/2)A
// (diag >= 1.05, no pivoting needed); A_bar = 2*Minv - I; 11 squarings.
// ---------------------------------------------------------------------------
__global__ __launch_bounds__(128) void k_setup(const float* __restrict__ A,
                                               const float* __restrict__ logdt,
                                               float* __restrict__ ws) {
  __shared__ float Msh[64 * 65];
  __shared__ float Tm[64 * 65];
  __shared__ float tmpb[1024];
  __shared__ __align__(16) float bufA[64 * PAD];
  __shared__ __align__(16) float bufB[64 * PAD];
  const int tid = threadIdx.x;
  const float dt = expf(logdt[0]);
  const float hdt = 0.5f * dt;
  if (tid == 0) ws[WS_DT] = dt;

  for (int idx = tid; idx < 4096; idx += 128) {
    const int i = idx >> 6, j = idx & 63;
    Msh[i * 65 + j] = ((i == j) ? 1.f : 0.f) - hdt * A[idx];
    Tm[i * 65 + j] = 0.f;
  }
  __syncthreads();
  if (tid < 64) Tm[tid * 65 + tid] = 1.0f / Msh[tid * 65 + tid];
  __syncthreads();

  // Recursive doubling: at level b, diagonal b-blocks of Tm hold inv(M_bb);
  // fill the (2b)-block off-diagonal: T21 = -T22 * M21 * T11.
  for (int lb = 0; lb < 6; ++lb) {
    const int b = 1 << lb;
    const int E = 32 * b;  // (64/2b) pairs * b*b elements
    for (int e = tid; e < E; e += 128) {
      const int rem = e & (b * b - 1);
      const int p = e >> (2 * lb);
      const int i = rem >> lb, j = rem & (b - 1);
      const int c0 = p << (lb + 1), r0 = c0 + b;
      float s = 0.f;
      for (int k = 0; k < b; ++k)
        s += Msh[(r0 + i) * 65 + c0 + k] * Tm[(c0 + k) * 65 + c0 + j];
      tmpb[e] = s;
    }
    __syncthreads();
    for (int e = tid; e < E; e += 128) {
      const int rem = e & (b * b - 1);
      const int p = e >> (2 * lb);
      const int i = rem >> lb, j = rem & (b - 1);
      const int c0 = p << (lb + 1), r0 = c0 + b;
      float s = 0.f;
      const float* tp = &tmpb[e - rem];
      for (int k = 0; k < b; ++k)
        s += Tm[(r0 + i) * 65 + r0 + k] * tp[k * b + j];
      Tm[(r0 + i) * 65 + c0 + j] = -s;
    }
    __syncthreads();
  }

  // Minv^T to ws (for B_bar), stride-65 transposed read is conflict-free.
  for (int idx = tid; idx < 4096; idx += 128) {
    const int k = idx >> 6, n = idx & 63;
    ws[WS_MINVT + idx] = Tm[n * 65 + k];
  }
  // A_bar = 2*Minv - I -> bufA (padded) and ws S_0.
  for (int idx = tid; idx < 4096; idx += 128) {
    const int i = idx >> 6, j = idx & 63;
    const float v = 2.f * Tm[i * 65 + j] - ((i == j) ? 1.f : 0.f);
    bufA[i * PAD + j] = v;
    ws[WS_S + idx] = v;
  }
  __syncthreads();

  float* cur = bufA;
  float* nxt = bufB;
  for (int sj = 1; sj < 12; ++sj) {
    mm64_128(cur, cur, nxt, tid);
    __syncthreads();  // nxt complete before unstage / next mm reads
    unstage<128>(nxt, ws + WS_S + sj * 4096, tid, 1.f);
    float* t = cur; cur = nxt; nxt = t;
    // no extra barrier needed: next mm writes old cur (nobody reads it),
    // reads new cur (covered by the barrier above).
  }
}

// ---------------------------------------------------------------------------
// K2: 144 blocks x 128.
//   p in [0,64):    G_r  = prod S_j over set bits of r   (row-major)
//   p in [64,128):  H_q^T (transposed store)
//   p in [128,144): B_bar chunk: dt * B_chunk @ Minv^T
// cur initialized from the lowest set bit -> <= popcount-1 multiplies.
// ---------------------------------------------------------------------------
__global__ __launch_bounds__(128) void k_powers(const float* __restrict__ Bg,
                                                float* __restrict__ ws) {
  __shared__ __align__(16) float ra[64 * PAD];
  __shared__ __align__(16) float rb[64 * PAD];
  __shared__ __align__(16) float sm[64 * PAD];
  const int p = blockIdx.x, tid = threadIdx.x;

  if (p < 128) {
    const int chain = p >> 6, r = p & 63;
    float* cur = ra;
    float* nxt = rb;
    if (r == 0) {
      for (int idx = tid; idx < 4096; idx += 128) {
        const int i = idx >> 6, j = idx & 63;
        cur[i * PAD + j] = (i == j) ? 1.f : 0.f;
      }
    } else {
      const int j0 = __ffs(r) - 1;
      stage<128>(ws + WS_S + (chain * 6 + j0) * 4096, cur, tid);
      for (int j = j0 + 1; j < 6; ++j) {
        if ((r >> j) & 1) {  // block-uniform branch
          __syncthreads();   // cur staged / prior mm's sm reads done
          stage<128>(ws + WS_S + (chain * 6 + j) * 4096, sm, tid);
          __syncthreads();
          mm64_128(cur, sm, nxt, tid);
          __syncthreads();   // nxt complete
          float* t = cur; cur = nxt; nxt = t;
        }
      }
    }
    __syncthreads();
    if (chain == 0) {
      unstage<128>(cur, ws + WS_G + r * 4096, tid, 1.f);
    } else {
      // HT[k][n] = H[n][k]
      float* HT = ws + WS_HT + r * 4096;
      for (int idx = tid; idx < 4096; idx += 128) {
        const int k = idx >> 6, n = idx & 63;
        HT[idx] = cur[n * PAD + k];
      }
    }
  } else {
    const int d0 = (p - 128) * 64;
    stage<128>(ws + WS_MINVT, sm, tid);
    stage<128>(Bg + d0 * 64, ra, tid);
    __syncthreads();
    mm64_128(ra, sm, rb, tid);
    __syncthreads();
    unstage<128>(rb, ws + WS_BBAR + d0 * 64, tid, ws[WS_DT]);
  }
}

// ---------------------------------------------------------------------------
// K3: 1024 blocks x 128 (2 waves, each wave owns one r = rp*2+wave).
// chain0: W[d0.., r, :] = C_chunk @ G_r; chain1: X[d0.., q, :] = Bbar @ H_q^T
// 8x(4+4) register tiles; rows interleaved i = ty + 8*ii for conflict-free
// a-reads; cols n in {4tx, 4tx+32}.
// ---------------------------------------------------------------------------
__global__ __launch_bounds__(128) void k_expand(const float* __restrict__ Cg,
                                                float* __restrict__ ws) {
  __shared__ __align__(16) float matL[2][64 * PAD];
  __shared__ __align__(16) float srcL[64 * PAD];
  const int p = blockIdx.x, tid = threadIdx.x;
  const int chain = p >> 9, rp = (p >> 4) & 31, dch = p & 15;
  const int wave = tid >> 6, lt = tid & 63;
  const int d0 = dch * 64;
  const int rr = rp * 2 + wave;
  const float* msrc = ws + (chain ? WS_HT : WS_G) + rr * 4096;
  const float* vsrc = chain ? (ws + WS_BBAR + d0 * 64) : (Cg + d0 * 64);

  for (int e = lt; e < 1024; e += 64) {  // each wave stages its own mat
    const int row = e >> 4, c4 = (e & 15) << 2;
    *(float4*)&matL[wave][row * PAD + c4] = *(const float4*)&msrc[row * 64 + c4];
  }
  stage<128>(vsrc, srcL, tid);
  __syncthreads();

  const int tx = lt & 7, ty = lt >> 3;
  const float* mw = matL[wave];
  float4 acc[8][2];
#pragma unroll
  for (int ii = 0; ii < 8; ++ii) {
    acc[ii][0] = make_float4(0.f, 0.f, 0.f, 0.f);
    acc[ii][1] = make_float4(0.f, 0.f, 0.f, 0.f);
  }
  for (int k = 0; k < 64; k += 4) {
    float4 av[8];
#pragma unroll
    for (int ii = 0; ii < 8; ++ii)
      av[ii] = *(const float4*)&srcL[(ty + 8 * ii) * PAD + k];
#pragma unroll
    for (int kk = 0; kk < 4; ++kk) {
      const float4 b0 = *(const float4*)&mw[(k + kk) * PAD + 4 * tx];
      const float4 b1 = *(const float4*)&mw[(k + kk) * PAD + 4 * tx + 32];
#pragma unroll
      for (int ii = 0; ii < 8; ++ii) {
        const float s = f4c(av[ii], kk);
        acc[ii][0].x += s * b0.x; acc[ii][0].y += s * b0.y;
        acc[ii][0].z += s * b0.z; acc[ii][0].w += s * b0.w;
        acc[ii][1].x += s * b1.x; acc[ii][1].y += s * b1.y;
        acc[ii][1].z += s * b1.z; acc[ii][1].w += s * b1.w;
      }
    }
  }
  float* dst = ws + (chain ? WS_X : WS_W);
#pragma unroll
  for (int ii = 0; ii < 8; ++ii) {
    const int row = d0 + ty + 8 * ii;
    *(float4*)&dst[row * 4096 + rr * 64 + 4 * tx] = acc[ii][0];
    *(float4*)&dst[row * 4096 + rr * 64 + 4 * tx + 32] = acc[ii][1];
  }
}

// ---------------------------------------------------------------------------
// K4: 1024 blocks x 64, one block per d. NT-GEMM K[r][q] = sum_n W[r,n]X[q,n].
// 4x16 tiles: r = rty + 16*ii (conflict-free W reads, 64B-coalesced stores),
// q = qtx + 4*jj (4 broadcast spans). + D[d] at l==0.
// ---------------------------------------------------------------------------
__global__ __launch_bounds__(64) void k_contract(const float* __restrict__ Dg,
                                                 const float* __restrict__ ws,
                                                 float* __restrict__ out) {
  __shared__ __align__(16) float Wl[64 * PAD];
  __shared__ __align__(16) float Xl[64 * PAD];
  const int d = blockIdx.x, tid = threadIdx.x;
  stage<64>(ws + WS_W + d * 4096, Wl, tid);
  stage<64>(ws + WS_X + d * 4096, Xl, tid);
  __syncthreads();

  const int rty = tid & 15, qtx = tid >> 4;
  float acc[4][16];
#pragma unroll
  for (int ii = 0; ii < 4; ++ii)
#pragma unroll
    for (int jj = 0; jj < 16; ++jj) acc[ii][jj] = 0.f;

  for (int nn = 0; nn < 64; nn += 4) {
    float4 av[4];
#pragma unroll
    for (int ii = 0; ii < 4; ++ii)
      av[ii] = *(const float4*)&Wl[(rty + 16 * ii) * PAD + nn];
#pragma unroll
    for (int jj = 0; jj < 16; ++jj) {
      const float4 bv = *(const float4*)&Xl[(qtx + 4 * jj) * PAD + nn];
#pragma unroll
      for (int ii = 0; ii < 4; ++ii) {
        acc[ii][jj] += av[ii].x * bv.x + av[ii].y * bv.y +
                       av[ii].z * bv.z + av[ii].w * bv.w;
      }
    }
  }
  const float dval = Dg[d];
  float* od = out + d * 4096;
#pragma unroll
  for (int jj = 0; jj < 16; ++jj) {
#pragma unroll
    for (int ii = 0; ii < 4; ++ii) {
      const int q = qtx + 4 * jj, r = rty + 16 * ii;
      const int l = q * 64 + r;
      od[l] = acc[ii][jj] + ((l == 0) ? dval : 0.f);
    }
  }
}

extern "C" void kernel_launch(void* const* d_in, const int* in_sizes, int n_in,
                              void* d_out, int out_size, void* d_ws, size_t ws_size,
                              hipStream_t stream) {
  const float* A     = (const float*)d_in[0];  // A_ct 64x64
  const float* B     = (const float*)d_in[1];  // 1024x64
  const float* C     = (const float*)d_in[2];  // 1024x64
  const float* Dv    = (const float*)d_in[3];  // 1024
  const float* logdt = (const float*)d_in[4];  // scalar
  float* ws  = (float*)d_ws;                   // 36.2 MB
  float* out = (float*)d_out;                  // 1024*4096 fp32

  hipLaunchKernelGGL(k_setup,    dim3(1),    dim3(128), 0, stream, A, logdt, ws);
  hipLaunchKernelGGL(k_powers,   dim3(144),  dim3(128), 0, stream, B, ws);
  hipLaunchKernelGGL(k_expand,   dim3(1024), dim3(128), 0, stream, C, ws);
  hipLaunchKernelGGL(k_contract, dim3(1024), dim3(64),  0, stream, Dv, ws, out);
}